// Round 14
// baseline (509.065 us; speedup 1.0000x reference)
//
#include <hip/hip_runtime.h>
#include <cstdint>
#include <cstddef>

#define NN 50000
#define NE 800000
#define HID 256
#define TDIM 128

#define CHB 16384          // bins per histogram chunk (64 KB LDS)
#define NSL 16             // edge slices
#define SLE (NE / NSL)     // 50000 edges per slice

typedef short bf16x8 __attribute__((ext_vector_type(8)));
typedef float f32x4 __attribute__((ext_vector_type(4)));

#define GLOAD_LDS16(g, l)                                                        \
  __builtin_amdgcn_global_load_lds(                                              \
      (const __attribute__((address_space(1))) unsigned int*)(g),                \
      (__attribute__((address_space(3))) unsigned int*)(l), 16, 0, 0)

__device__ inline unsigned short f2bf(float f) {
  uint32_t u = __builtin_bit_cast(uint32_t, f);
  uint32_t r = u + 0x7FFFu + ((u >> 16) & 1u);
  return (unsigned short)(r >> 16);
}
__device__ inline float bf2f(unsigned short s) {
  uint32_t u = ((uint32_t)s) << 16;
  return __builtin_bit_cast(float, u);
}
__device__ inline float fast_sig(float x) {
  return __builtin_amdgcn_rcpf(1.0f + __expf(-x));
}
__device__ inline float fast_tanh(float x) {
  float xc = fminf(fmaxf(x, -10.0f), 10.0f);
  float e = __expf(2.0f * xc);
  return 1.0f - 2.0f * __builtin_amdgcn_rcpf(e + 1.0f);
}

// ---------------- hidden -> bf16 plane ----------------
__global__ __launch_bounds__(256) void cvt_hidden(const float* __restrict__ x,
                                                  short* __restrict__ xb) {
  int i = blockIdx.x * 256 + threadIdx.x;
  if (i < NN * HID / 4) {
    float4 v = ((const float4*)x)[i];
    unsigned int lo = (unsigned int)f2bf(v.x) | ((unsigned int)f2bf(v.y) << 16);
    unsigned int hi = (unsigned int)f2bf(v.z) | ((unsigned int)f2bf(v.w) << 16);
    ((uint2*)xb)[i] = make_uint2(lo, hi);
  }
}

// ---------------- histogram phase A ----------------
__global__ __launch_bounds__(1024) void hist_part(const int* __restrict__ src,
                                                  const int* __restrict__ dst,
                                                  int* __restrict__ P) {
  __shared__ int h[CHB];
  const int b = blockIdx.x;          // 8 * NSL blocks
  const int c = b & 7, s = b >> 3;
  for (int j = threadIdx.x; j < CHB; j += 1024) h[j] = 0;
  __syncthreads();
  const int* arr = (c < 4) ? src : dst;
  const int base = (c & 3) * CHB;
  const int e0 = s * SLE;
  for (int i = threadIdx.x; i < SLE; i += 1024) {
    int v = arr[e0 + i] - base;
    if ((unsigned)v < CHB) atomicAdd(&h[v], 1);
  }
  __syncthreads();
  int* Pc = P + (size_t)(c * NSL + s) * CHB;
  for (int j = threadIdx.x; j < CHB; j += 1024) Pc[j] = h[j];
}

// ---------------- phase B: reduce -> norms; in-place slice scan ----------------
__global__ __launch_bounds__(256) void hist_reduce(int* __restrict__ P,
                                                   float* __restrict__ onorm,
                                                   float* __restrict__ inorm,
                                                   int* __restrict__ icnt) {
  int n = blockIdx.x * 256 + threadIdx.x;
  if (n >= 4 * CHB) return;
  const int c = n >> 14, j = n & (CHB - 1);
  int* Po = P + (size_t)(c * NSL) * CHB + j;
  int od = 0;
#pragma unroll
  for (int s = 0; s < NSL; ++s) od += Po[(size_t)s * CHB];
  int* Pi = P + (size_t)((4 + c) * NSL) * CHB + j;
  int run = 0;
#pragma unroll
  for (int s = 0; s < NSL; ++s) { int t = Pi[(size_t)s * CHB]; Pi[(size_t)s * CHB] = run; run += t; }
  if (n < NN) {
    onorm[n] = 1.0f / sqrtf(fmaxf((float)od, 1.0f));
    inorm[n] = 1.0f / sqrtf(fmaxf((float)run, 1.0f));
    icnt[n] = run;
  }
}

// ---------------- CSR row scan ----------------
__global__ __launch_bounds__(1024) void scan_rows(const int* __restrict__ icnt,
                                                  int* __restrict__ rowstart) {
  __shared__ int wsum[16];
  __shared__ int carry_s;
  const int tid = threadIdx.x, lane = tid & 63, w = tid >> 6;
  if (tid == 0) { carry_s = 0; rowstart[0] = 0; }
  __syncthreads();
  for (int base = 0; base < NN; base += 8192) {
    int i0 = base + tid * 8;
    int c[8];
    int v = 0;
#pragma unroll
    for (int j = 0; j < 8; ++j) {
      int i = i0 + j;
      c[j] = (i < NN) ? icnt[i] : 0;
      v += c[j];
    }
    int inc = v;
#pragma unroll
    for (int off = 1; off < 64; off <<= 1) {
      int t = __shfl_up(inc, off, 64);
      if (lane >= off) inc += t;
    }
    if (lane == 63) wsum[w] = inc;
    __syncthreads();
    int woff = 0;
    for (int k = 0; k < w; ++k) woff += wsum[k];
    int carry = carry_s;
    int run = carry + woff + inc - v;
#pragma unroll
    for (int j = 0; j < 8; ++j) {
      int i = i0 + j;
      if (i < NN) rowstart[i + 1] = run + c[j];
      run += c[j];
    }
    __syncthreads();
    if (tid == 1023) carry_s = carry + woff + inc;
    __syncthreads();
  }
}

// ---------------- CSR fill via LDS cursors ----------------
__global__ __launch_bounds__(1024) void fill_csr2(const int* __restrict__ src,
                                                  const int* __restrict__ dst,
                                                  const float* __restrict__ onorm,
                                                  const int* __restrict__ rowstart,
                                                  const int* __restrict__ P,
                                                  int* __restrict__ col,
                                                  float* __restrict__ ewt) {
  __shared__ int cur[CHB];
  const int b = blockIdx.x;          // 4 * NSL blocks
  const int c = b & 3, s = b >> 2;
  const int base = c * CHB;
  const int* Pi = P + (size_t)((4 + c) * NSL + s) * CHB;
  for (int j = threadIdx.x; j < CHB; j += 1024) {
    int n = base + j;
    cur[j] = (n < NN ? rowstart[n] : 0) + Pi[j];
  }
  __syncthreads();
  const int e0 = s * SLE;
  for (int i = threadIdx.x; i < SLE; i += 1024) {
    int d = dst[e0 + i] - base;
    if ((unsigned)d < CHB) {
      int sv = src[e0 + i];
      int pos = atomicAdd(&cur[d], 1);
      col[pos] = sv;
      ewt[pos] = onorm[sv];
    }
  }
}

// ---------------- fused weight prep ----------------
__global__ __launch_bounds__(256) void wprep(const float* __restrict__ W1,
                                             const float* __restrict__ W2,
                                             const float* __restrict__ W_ih,
                                             const float* __restrict__ W_hh,
                                             const float* __restrict__ t,
                                             const float* __restrict__ tw,
                                             const float* __restrict__ tb,
                                             const float* __restrict__ b_ih,
                                             const float* __restrict__ b_hh,
                                             short* __restrict__ W1B,
                                             short* __restrict__ W2B,
                                             short* __restrict__ WgB,
                                             float* __restrict__ cst) {
  const int b = blockIdx.x;
  const int k = threadIdx.x;
  if (b < 256) {
    W1B[b * 256 + k] = (short)f2bf(W1[k * 256 + b]);
    W2B[b * 256 + k] = (short)f2bf(W2[k * 256 + b]);
  } else if (b < 512) {
    int u = b - 256;
    int base = (u >> 4) * 64 + (u & 15);
    float v0 = W_ih[(size_t)u * 384 + k] + W_hh[(size_t)u * 256 + k];
    float v1 = W_ih[(size_t)(256 + u) * 384 + k] + W_hh[(size_t)(256 + u) * 256 + k];
    float v2 = W_ih[(size_t)(512 + u) * 384 + k];
    float v3 = W_hh[(size_t)(512 + u) * 256 + k];
    WgB[(size_t)(base + 0)  * 256 + k] = (short)f2bf(v0);
    WgB[(size_t)(base + 16) * 256 + k] = (short)f2bf(v1);
    WgB[(size_t)(base + 32) * 256 + k] = (short)f2bf(v2);
    WgB[(size_t)(base + 48) * 256 + k] = (short)f2bf(v3);
  } else {
    __shared__ float te[TDIM];
    int u = k;
    if (u < TDIM) te[u] = cosf(t[0] * tw[u] + tb[u]);
    __syncthreads();
    float cr = b_ih[u] + b_hh[u];
    float cz = b_ih[256 + u] + b_hh[256 + u];
    float ci = b_ih[512 + u];
    for (int kk = 0; kk < TDIM; ++kk) {
      float tk = te[kk];
      cr = fmaf(tk, W_ih[(size_t)u * 384 + 256 + kk], cr);
      cz = fmaf(tk, W_ih[(size_t)(256 + u) * 384 + 256 + kk], cz);
      ci = fmaf(tk, W_ih[(size_t)(512 + u) * 384 + 256 + kk], ci);
    }
    cst[u] = cr;
    cst[256 + u] = cz;
    cst[512 + u] = ci;
    cst[768 + u] = b_hh[512 + u];
  }
}

// ---------------- fused gather + GCN GEMM ----------------
// 64 dst rows per block (782 blocks), 4 waves, 64 KB LDS -> 2 blocks/CU.
// Phase G: each wave gathers 16 rows (8-edge unroll) -> bf16 into XOR-swizzled At.
// Phase M: A-frags read once from At; W panels (64 cols x 256 K = 32 KB) double-buffer
//          across {Ps, At} (At is dead after the frag read). relu(acc+bias) -> bf16 out.
__global__ __launch_bounds__(256, 2) void gather_gemm(const short* __restrict__ xB,
                                                      const int* __restrict__ rowstart,
                                                      const int* __restrict__ col,
                                                      const float* __restrict__ ewt,
                                                      const float* __restrict__ inorm,
                                                      const short* __restrict__ WB,
                                                      const float* __restrict__ bias,
                                                      short* __restrict__ outH) {
  __shared__ __align__(16) short At[64 * 256];   // 32 KB
  __shared__ __align__(16) short Ps[64 * 256];   // 32 KB

  const int row0 = blockIdx.x * 64;
  const int tid = threadIdx.x;
  const int l = tid & 63, w = tid >> 6;
  const int fr = l & 15, fg = l >> 4;

  // stage W panel 0 into Ps (XOR pre-swizzled source, linear LDS dest)
#pragma unroll
  for (int i = 0; i < 8; ++i) {
    int id = tid + i * 256;
    int row = id >> 5, kc = id & 31;
    GLOAD_LDS16(WB + (size_t)row * HID + ((kc ^ (row & 15)) << 3), Ps + id * 8);
  }

  // ---- phase G: gather 16 rows per wave into At ----
  const int fo = l * 4;
  for (int i = 0; i < 16; ++i) {
    int wid = row0 + w * 16 + i;
    float a0 = 0.f, a1 = 0.f, a2 = 0.f, a3 = 0.f;
    if (wid < NN) {
      int e = rowstart[wid];
      const int e1 = rowstart[wid + 1];
      for (; e + 8 <= e1; e += 8) {
        int ss[8]; float ww[8]; uint2 uu[8];
#pragma unroll
        for (int q = 0; q < 8; ++q) { ss[q] = col[e + q]; ww[q] = ewt[e + q]; }
#pragma unroll
        for (int q = 0; q < 8; ++q) uu[q] = *(const uint2*)(xB + (size_t)ss[q] * HID + fo);
#pragma unroll
        for (int q = 0; q < 8; ++q) {
          a0 = fmaf(bf2f((unsigned short)(uu[q].x & 0xFFFF)), ww[q], a0);
          a1 = fmaf(bf2f((unsigned short)(uu[q].x >> 16)),    ww[q], a1);
          a2 = fmaf(bf2f((unsigned short)(uu[q].y & 0xFFFF)), ww[q], a2);
          a3 = fmaf(bf2f((unsigned short)(uu[q].y >> 16)),    ww[q], a3);
        }
      }
      for (; e < e1; ++e) {
        int s0 = col[e];
        float w0 = ewt[e];
        uint2 u0 = *(const uint2*)(xB + (size_t)s0 * HID + fo);
        a0 = fmaf(bf2f((unsigned short)(u0.x & 0xFFFF)), w0, a0);
        a1 = fmaf(bf2f((unsigned short)(u0.x >> 16)),    w0, a1);
        a2 = fmaf(bf2f((unsigned short)(u0.y & 0xFFFF)), w0, a2);
        a3 = fmaf(bf2f((unsigned short)(u0.y >> 16)),    w0, a3);
      }
      float wi = inorm[wid];
      a0 *= wi; a1 *= wi; a2 *= wi; a3 *= wi;
    }
    // lane owns 8B (cols fo..fo+3): chunk m=l>>1, half=l&1, slot = m ^ (row&15)=m^i
    int slot = (l >> 1) ^ i;
    unsigned int b0 = (unsigned int)f2bf(a0) | ((unsigned int)f2bf(a1) << 16);
    unsigned int b1 = (unsigned int)f2bf(a2) | ((unsigned int)f2bf(a3) << 16);
    *(uint2*)&At[(w * 16 + i) * 256 + slot * 8 + (l & 1) * 4] = make_uint2(b0, b1);
  }
  __syncthreads();   // gather + panel0 landed

  // ---- A-frags from At (read once; reused for all 4 panels) ----
  bf16x8 af[8];
#pragma unroll
  for (int t = 0; t < 8; ++t)
    af[t] = *(const bf16x8*)&At[(w * 16 + fr) * 256 + (((t * 4 + fg) ^ fr) << 3)];
  __syncthreads();   // all waves done reading At -> reusable as panel buffer

  auto stage = [&](short* dst, int pidx) {
#pragma unroll
    for (int i = 0; i < 8; ++i) {
      int id = tid + i * 256;
      int row = id >> 5, kc = id & 31;
      GLOAD_LDS16(WB + (size_t)(pidx * 64 + row) * HID + ((kc ^ (row & 15)) << 3), dst + id * 8);
    }
  };
  auto comp = [&](const short* src, int ct) {
    f32x4 acc[4];
    acc[0] = acc[1] = acc[2] = acc[3] = (f32x4)(0.0f);
#pragma unroll
    for (int t = 0; t < 8; ++t) {
#pragma unroll
      for (int nf = 0; nf < 4; ++nf) {
        int rr = nf * 16 + fr;
        bf16x8 bh = *(const bf16x8*)&src[rr * 256 + (((t * 4 + fg) ^ (rr & 15)) << 3)];
        acc[nf] = __builtin_amdgcn_mfma_f32_16x16x32_bf16(af[t], bh, acc[nf], 0, 0, 0);
      }
    }
#pragma unroll
    for (int nf = 0; nf < 4; ++nf) {
      int c = ct * 64 + nf * 16 + fr;
      float bs = bias[c];
#pragma unroll
      for (int j = 0; j < 4; ++j) {
        int row = row0 + w * 16 + fg * 4 + j;
        if (row < NN) {
          float v = fmaxf(acc[nf][j] + bs, 0.0f);
          outH[(size_t)row * HID + c] = (short)f2bf(v);
        }
      }
    }
  };

  stage(At, 1);
  comp(Ps, 0);
  __syncthreads();
  stage(Ps, 2);
  comp(At, 1);
  __syncthreads();
  stage(At, 3);
  comp(Ps, 2);
  __syncthreads();
  comp(At, 3);
}

// ---------------- GRU GEMM (v5 structure: dbuf, 128x128, occ 4) ----------------
// CT=8 col-tiles over 1024 Wg cols; fused gate epilogue; carry from bf16 h plane.
template <int CT>
__global__ __launch_bounds__(256, 4) void gemm_gru(const short* __restrict__ A,
                                                   const short* __restrict__ B,
                                                   const float* __restrict__ cst,
                                                   float* __restrict__ outF) {
  __shared__ __align__(16) short As[2][128 * 32];
  __shared__ __align__(16) short Bs[2][128 * 32];

  const int nwg = gridDim.x;
  const int xcd = blockIdx.x & 7, jj = blockIdx.x >> 3;
  const int q = nwg >> 3, r = nwg & 7;
  const int lidx = (xcd < r ? xcd * (q + 1) : r * (q + 1) + (xcd - r) * q) + jj;
  const int strip = lidx / CT;
  const int ct = lidx % CT;
  const int row0 = strip * 128;
  const int col0 = ct * 128;

  const int tid = threadIdx.x;
  const int l = tid & 63, wv = tid >> 6;
  const int wm = wv >> 1, wn = wv & 1;
  const int fr = l & 15, fg = l >> 4;

  int arow[2], asw[2], brow[2];
#pragma unroll
  for (int i = 0; i < 2; ++i) {
    int id = tid + i * 256;
    int row = id >> 2, sp = id & 3;
    int s = (sp - (row >> 1)) & 3;
    int gr = row0 + row;
    arow[i] = (gr < NN ? gr : NN - 1);
    asw[i] = s;
    brow[i] = col0 + row;
  }

  f32x4 acc[4][4];
#pragma unroll
  for (int i = 0; i < 4; ++i)
#pragma unroll
    for (int j = 0; j < 4; ++j) acc[i][j] = (f32x4)(0.0f);

#pragma unroll
  for (int i = 0; i < 2; ++i) {
    int id = tid + i * 256;
    GLOAD_LDS16(A + (size_t)arow[i] * HID + asw[i] * 8, &As[0][id * 8]);
    GLOAD_LDS16(B + (size_t)brow[i] * HID + asw[i] * 8, &Bs[0][id * 8]);
  }
  __syncthreads();

#pragma unroll
  for (int t = 0; t < 8; ++t) {
    const int buf = t & 1;
    if (t < 7) {
      const int kn = (t + 1) * 32;
#pragma unroll
      for (int i = 0; i < 2; ++i) {
        int id = tid + i * 256;
        GLOAD_LDS16(A + (size_t)arow[i] * HID + kn + asw[i] * 8, &As[buf ^ 1][id * 8]);
        GLOAD_LDS16(B + (size_t)brow[i] * HID + kn + asw[i] * 8, &Bs[buf ^ 1][id * 8]);
      }
    }
    bf16x8 bh[4];
#pragma unroll
    for (int nf = 0; nf < 4; ++nf) {
      int rr = wn * 64 + nf * 16 + fr;
      bh[nf] = *(const bf16x8*)(&Bs[buf][rr * 32 + (((fg + (rr >> 1)) & 3) << 3)]);
    }
#pragma unroll
    for (int mf = 0; mf < 4; ++mf) {
      int rr = wm * 64 + mf * 16 + fr;
      bf16x8 ah = *(const bf16x8*)(&As[buf][rr * 32 + (((fg + (rr >> 1)) & 3) << 3)]);
#pragma unroll
      for (int nf = 0; nf < 4; ++nf)
        acc[mf][nf] = __builtin_amdgcn_mfma_f32_16x16x32_bf16(ah, bh[nf], acc[mf][nf], 0, 0, 0);
    }
    __syncthreads();
  }

  const int u = (ct * 2 + wn) * 16 + fr;
  const float cr = cst[u], cz = cst[256 + u], ci = cst[512 + u], chn = cst[768 + u];
#pragma unroll
  for (int mf = 0; mf < 4; ++mf) {
    int rbase = row0 + wm * 64 + mf * 16 + fg * 4;
#pragma unroll
    for (int j = 0; j < 4; ++j) {
      int row = rbase + j;
      if (row < NN) {
        float dr = acc[mf][0][j] + cr;
        float dz = acc[mf][1][j] + cz;
        float dn = acc[mf][2][j] + ci;
        float dh = acc[mf][3][j] + chn;
        float rg = fast_sig(dr);
        float zg = fast_sig(dz);
        float ng = fast_tanh(dn + rg * dh);
        size_t off = (size_t)row * HID + u;
        float hv = bf2f((unsigned short)A[off]);
        outF[off] = (1.0f - zg) * ng + zg * hv;
      }
    }
  }
}

extern "C" void kernel_launch(void* const* d_in, const int* in_sizes, int n_in,
                              void* d_out, int out_size, void* d_ws, size_t ws_size,
                              hipStream_t stream) {
  const float* hidden = (const float*)d_in[0];
  const float* t      = (const float*)d_in[1];
  const int*   src    = (const int*)d_in[2];
  const int*   dst    = (const int*)d_in[3];
  const float* W1     = (const float*)d_in[4];
  const float* b1     = (const float*)d_in[5];
  const float* W2     = (const float*)d_in[6];
  const float* b2     = (const float*)d_in[7];
  const float* time_w = (const float*)d_in[8];
  const float* time_b = (const float*)d_in[9];
  const float* W_ih   = (const float*)d_in[10];
  const float* W_hh   = (const float*)d_in[11];
  const float* b_ih   = (const float*)d_in[12];
  const float* b_hh   = (const float*)d_in[13];
  float* out = (float*)d_out;

  char* p = (char*)d_ws;
  float* onorm = (float*)p;      p += 50048 * 4;
  float* inorm = (float*)p;      p += 50048 * 4;
  float* cst   = (float*)p;      p += 1024 * 4;
  int* rowstart = (int*)p;       p += 50052 * 4;
  int* icnt     = (int*)p;       p += 50048 * 4;
  int* ecol     = (int*)p;       p += 800000 * 4;
  float* ewt    = (float*)p;     p += 800000 * 4;
  const size_t NFE = (size_t)NN * HID;
  short* Xb   = (short*)p;       p += NFE * 2;
  short* h1B  = (short*)p;       p += NFE * 2;
  short* h2B  = (short*)p;       p += NFE * 2;
  short* W1B  = (short*)p;       p += 65536 * 2;
  short* W2B  = (short*)p;       p += 65536 * 2;
  short* WgB  = (short*)p;       p += 262144 * 2;
  // partial-histogram workspace aliases h1B (8*NSL*CHB ints = 8.4 MB < 25.6 MB);
  // fill_csr2 consumes P before gather_gemm L1 first writes h1B (stream-ordered).
  int* P = (int*)h1B;

  // independent prep first
  cvt_hidden<<<(NN * HID / 4 + 255) / 256, 256, 0, stream>>>(hidden, Xb);
  wprep<<<513, 256, 0, stream>>>(W1, W2, W_ih, W_hh, t, time_w, time_b, b_ih, b_hh,
                                 W1B, W2B, WgB, cst);

  // graph prep: privatized histograms -> norms/prefix -> row scan -> LDS-cursor fill
  hist_part<<<8 * NSL, 1024, 0, stream>>>(src, dst, P);
  hist_reduce<<<(4 * CHB + 255) / 256, 256, 0, stream>>>(P, onorm, inorm, icnt);
  scan_rows<<<1, 1024, 0, stream>>>(icnt, rowstart);
  fill_csr2<<<4 * NSL, 1024, 0, stream>>>(src, dst, onorm, rowstart, P, ecol, ewt);

  const int gblocks = (NN + 63) / 64;   // 782
  const int strips = (NN + 127) / 128;  // 391

  // layer 1: fused gather + GEMM  (Xb -> h1B)
  gather_gemm<<<gblocks, 256, 0, stream>>>(Xb, rowstart, ecol, ewt, inorm, W1B, b1, h1B);

  // layer 2: fused gather + GEMM  (h1B -> h2B)
  gather_gemm<<<gblocks, 256, 0, stream>>>(h1B, rowstart, ecol, ewt, inorm, W2B, b2, h2B);

  // GRU: v5-structure GEMM (dbuf, 128x128, occ 4), carry from h2B -> out
  gemm_gru<8><<<strips * 8, 256, 0, stream>>>(h2B, WgB, cst, out);
}

// Round 15
// 494.325 us; speedup vs baseline: 1.0298x; 1.0298x over previous
//
#include <hip/hip_runtime.h>
#include <cstdint>
#include <cstddef>

#define NN 50000
#define NE 800000
#define HID 256
#define TDIM 128

#define CHB 16384          // bins per histogram chunk (64 KB LDS)
#define NSL 16             // edge slices
#define SLE (NE / NSL)     // 50000 edges per slice

typedef short bf16x8 __attribute__((ext_vector_type(8)));
typedef float f32x4 __attribute__((ext_vector_type(4)));

__device__ inline unsigned short f2bf(float f) {
  uint32_t u = __builtin_bit_cast(uint32_t, f);
  uint32_t r = u + 0x7FFFu + ((u >> 16) & 1u);
  return (unsigned short)(r >> 16);
}
__device__ inline float bf2f(unsigned short s) {
  uint32_t u = ((uint32_t)s) << 16;
  return __builtin_bit_cast(float, u);
}
__device__ inline float fast_sig(float x) {
  return __builtin_amdgcn_rcpf(1.0f + __expf(-x));
}
__device__ inline float fast_tanh(float x) {
  float xc = fminf(fmaxf(x, -10.0f), 10.0f);
  float e = __expf(2.0f * xc);
  return 1.0f - 2.0f * __builtin_amdgcn_rcpf(e + 1.0f);
}

// ---------------- hidden -> bf16 plane ----------------
__global__ __launch_bounds__(256) void cvt_hidden(const float* __restrict__ x,
                                                  short* __restrict__ xb) {
  int i = blockIdx.x * 256 + threadIdx.x;
  if (i < NN * HID / 4) {
    float4 v = ((const float4*)x)[i];
    unsigned int lo = (unsigned int)f2bf(v.x) | ((unsigned int)f2bf(v.y) << 16);
    unsigned int hi = (unsigned int)f2bf(v.z) | ((unsigned int)f2bf(v.w) << 16);
    ((uint2*)xb)[i] = make_uint2(lo, hi);
  }
}

// ---------------- histogram phase A ----------------
__global__ __launch_bounds__(1024) void hist_part(const int* __restrict__ src,
                                                  const int* __restrict__ dst,
                                                  int* __restrict__ P) {
  __shared__ int h[CHB];
  const int b = blockIdx.x;          // 8 * NSL blocks
  const int c = b & 7, s = b >> 3;
  for (int j = threadIdx.x; j < CHB; j += 1024) h[j] = 0;
  __syncthreads();
  const int* arr = (c < 4) ? src : dst;
  const int base = (c & 3) * CHB;
  const int e0 = s * SLE;
  for (int i = threadIdx.x; i < SLE; i += 1024) {
    int v = arr[e0 + i] - base;
    if ((unsigned)v < CHB) atomicAdd(&h[v], 1);
  }
  __syncthreads();
  int* Pc = P + (size_t)(c * NSL + s) * CHB;
  for (int j = threadIdx.x; j < CHB; j += 1024) Pc[j] = h[j];
}

// ---------------- phase B: reduce -> norms; in-place slice scan ----------------
__global__ __launch_bounds__(256) void hist_reduce(int* __restrict__ P,
                                                   float* __restrict__ onorm,
                                                   float* __restrict__ inorm,
                                                   int* __restrict__ icnt) {
  int n = blockIdx.x * 256 + threadIdx.x;
  if (n >= 4 * CHB) return;
  const int c = n >> 14, j = n & (CHB - 1);
  int* Po = P + (size_t)(c * NSL) * CHB + j;
  int od = 0;
#pragma unroll
  for (int s = 0; s < NSL; ++s) od += Po[(size_t)s * CHB];
  int* Pi = P + (size_t)((4 + c) * NSL) * CHB + j;
  int run = 0;
#pragma unroll
  for (int s = 0; s < NSL; ++s) { int t = Pi[(size_t)s * CHB]; Pi[(size_t)s * CHB] = run; run += t; }
  if (n < NN) {
    onorm[n] = 1.0f / sqrtf(fmaxf((float)od, 1.0f));
    inorm[n] = 1.0f / sqrtf(fmaxf((float)run, 1.0f));
    icnt[n] = run;
  }
}

// ---------------- CSR row scan ----------------
__global__ __launch_bounds__(1024) void scan_rows(const int* __restrict__ icnt,
                                                  int* __restrict__ rowstart) {
  __shared__ int wsum[16];
  __shared__ int carry_s;
  const int tid = threadIdx.x, lane = tid & 63, w = tid >> 6;
  if (tid == 0) { carry_s = 0; rowstart[0] = 0; }
  __syncthreads();
  for (int base = 0; base < NN; base += 8192) {
    int i0 = base + tid * 8;
    int c[8];
    int v = 0;
#pragma unroll
    for (int j = 0; j < 8; ++j) {
      int i = i0 + j;
      c[j] = (i < NN) ? icnt[i] : 0;
      v += c[j];
    }
    int inc = v;
#pragma unroll
    for (int off = 1; off < 64; off <<= 1) {
      int t = __shfl_up(inc, off, 64);
      if (lane >= off) inc += t;
    }
    if (lane == 63) wsum[w] = inc;
    __syncthreads();
    int woff = 0;
    for (int k = 0; k < w; ++k) woff += wsum[k];
    int carry = carry_s;
    int run = carry + woff + inc - v;
#pragma unroll
    for (int j = 0; j < 8; ++j) {
      int i = i0 + j;
      if (i < NN) rowstart[i + 1] = run + c[j];
      run += c[j];
    }
    __syncthreads();
    if (tid == 1023) carry_s = carry + woff + inc;
    __syncthreads();
  }
}

// ---------------- CSR fill via LDS cursors ----------------
__global__ __launch_bounds__(1024) void fill_csr2(const int* __restrict__ src,
                                                  const int* __restrict__ dst,
                                                  const float* __restrict__ onorm,
                                                  const int* __restrict__ rowstart,
                                                  const int* __restrict__ P,
                                                  int* __restrict__ col,
                                                  float* __restrict__ ewt) {
  __shared__ int cur[CHB];
  const int b = blockIdx.x;          // 4 * NSL blocks
  const int c = b & 3, s = b >> 2;
  const int base = c * CHB;
  const int* Pi = P + (size_t)((4 + c) * NSL + s) * CHB;
  for (int j = threadIdx.x; j < CHB; j += 1024) {
    int n = base + j;
    cur[j] = (n < NN ? rowstart[n] : 0) + Pi[j];
  }
  __syncthreads();
  const int e0 = s * SLE;
  for (int i = threadIdx.x; i < SLE; i += 1024) {
    int d = dst[e0 + i] - base;
    if ((unsigned)d < CHB) {
      int sv = src[e0 + i];
      int pos = atomicAdd(&cur[d], 1);
      col[pos] = sv;
      ewt[pos] = onorm[sv];
    }
  }
}

// ---------------- gather aggregation (bf16 in -> bf16 out), 8-edge unroll ----------------
__global__ __launch_bounds__(256) void gather_agg(const short* __restrict__ xB,
                                                  const int* __restrict__ rowstart,
                                                  const int* __restrict__ col,
                                                  const float* __restrict__ ewt,
                                                  const float* __restrict__ inorm,
                                                  short* __restrict__ aggB) {
  const int wid = blockIdx.x * 4 + (threadIdx.x >> 6);
  const int lane = threadIdx.x & 63;
  if (wid >= NN) return;
  const int e1 = rowstart[wid + 1];
  int e = rowstart[wid];
  const int fo = lane * 4;
  float a[4] = {0.f, 0.f, 0.f, 0.f};
  for (; e + 8 <= e1; e += 8) {
    int ss[8]; float ww[8]; uint2 uu[8];
#pragma unroll
    for (int q = 0; q < 8; ++q) { ss[q] = col[e + q]; ww[q] = ewt[e + q]; }
#pragma unroll
    for (int q = 0; q < 8; ++q) uu[q] = *(const uint2*)(xB + (size_t)ss[q] * HID + fo);
#pragma unroll
    for (int q = 0; q < 8; ++q) {
      a[0] = fmaf(bf2f((unsigned short)(uu[q].x & 0xFFFF)), ww[q], a[0]);
      a[1] = fmaf(bf2f((unsigned short)(uu[q].x >> 16)),    ww[q], a[1]);
      a[2] = fmaf(bf2f((unsigned short)(uu[q].y & 0xFFFF)), ww[q], a[2]);
      a[3] = fmaf(bf2f((unsigned short)(uu[q].y >> 16)),    ww[q], a[3]);
    }
  }
  for (; e + 2 <= e1; e += 2) {
    int s0 = col[e], s1 = col[e + 1];
    float w0 = ewt[e], w1 = ewt[e + 1];
    uint2 u0 = *(const uint2*)(xB + (size_t)s0 * HID + fo);
    uint2 u1 = *(const uint2*)(xB + (size_t)s1 * HID + fo);
    a[0] = fmaf(bf2f((unsigned short)(u0.x & 0xFFFF)), w0, a[0]);
    a[1] = fmaf(bf2f((unsigned short)(u0.x >> 16)),    w0, a[1]);
    a[2] = fmaf(bf2f((unsigned short)(u0.y & 0xFFFF)), w0, a[2]);
    a[3] = fmaf(bf2f((unsigned short)(u0.y >> 16)),    w0, a[3]);
    a[0] = fmaf(bf2f((unsigned short)(u1.x & 0xFFFF)), w1, a[0]);
    a[1] = fmaf(bf2f((unsigned short)(u1.x >> 16)),    w1, a[1]);
    a[2] = fmaf(bf2f((unsigned short)(u1.y & 0xFFFF)), w1, a[2]);
    a[3] = fmaf(bf2f((unsigned short)(u1.y >> 16)),    w1, a[3]);
  }
  if (e < e1) {
    int s0 = col[e];
    float w0 = ewt[e];
    uint2 u0 = *(const uint2*)(xB + (size_t)s0 * HID + fo);
    a[0] = fmaf(bf2f((unsigned short)(u0.x & 0xFFFF)), w0, a[0]);
    a[1] = fmaf(bf2f((unsigned short)(u0.x >> 16)),    w0, a[1]);
    a[2] = fmaf(bf2f((unsigned short)(u0.y & 0xFFFF)), w0, a[2]);
    a[3] = fmaf(bf2f((unsigned short)(u0.y >> 16)),    w0, a[3]);
  }
  const float wi = inorm[wid];
  unsigned int lo = (unsigned int)f2bf(a[0] * wi) | ((unsigned int)f2bf(a[1] * wi) << 16);
  unsigned int hi = (unsigned int)f2bf(a[2] * wi) | ((unsigned int)f2bf(a[3] * wi) << 16);
  *(uint2*)(aggB + (size_t)wid * HID + fo) = make_uint2(lo, hi);
}

// ---------------- fused weight prep ----------------
__global__ __launch_bounds__(256) void wprep(const float* __restrict__ W1,
                                             const float* __restrict__ W2,
                                             const float* __restrict__ W_ih,
                                             const float* __restrict__ W_hh,
                                             const float* __restrict__ t,
                                             const float* __restrict__ tw,
                                             const float* __restrict__ tb,
                                             const float* __restrict__ b_ih,
                                             const float* __restrict__ b_hh,
                                             short* __restrict__ W1B,
                                             short* __restrict__ W2B,
                                             short* __restrict__ WgB,
                                             float* __restrict__ cst) {
  const int b = blockIdx.x;
  const int k = threadIdx.x;
  if (b < 256) {
    W1B[b * 256 + k] = (short)f2bf(W1[k * 256 + b]);
    W2B[b * 256 + k] = (short)f2bf(W2[k * 256 + b]);
  } else if (b < 512) {
    int u = b - 256;
    int base = (u >> 4) * 64 + (u & 15);
    float v0 = W_ih[(size_t)u * 384 + k] + W_hh[(size_t)u * 256 + k];
    float v1 = W_ih[(size_t)(256 + u) * 384 + k] + W_hh[(size_t)(256 + u) * 256 + k];
    float v2 = W_ih[(size_t)(512 + u) * 384 + k];
    float v3 = W_hh[(size_t)(512 + u) * 256 + k];
    WgB[(size_t)(base + 0)  * 256 + k] = (short)f2bf(v0);
    WgB[(size_t)(base + 16) * 256 + k] = (short)f2bf(v1);
    WgB[(size_t)(base + 32) * 256 + k] = (short)f2bf(v2);
    WgB[(size_t)(base + 48) * 256 + k] = (short)f2bf(v3);
  } else {
    __shared__ float te[TDIM];
    int u = k;
    if (u < TDIM) te[u] = cosf(t[0] * tw[u] + tb[u]);
    __syncthreads();
    float cr = b_ih[u] + b_hh[u];
    float cz = b_ih[256 + u] + b_hh[256 + u];
    float ci = b_ih[512 + u];
    for (int kk = 0; kk < TDIM; ++kk) {
      float tk = te[kk];
      cr = fmaf(tk, W_ih[(size_t)u * 384 + 256 + kk], cr);
      cz = fmaf(tk, W_ih[(size_t)(256 + u) * 384 + 256 + kk], cz);
      ci = fmaf(tk, W_ih[(size_t)(512 + u) * 384 + 256 + kk], ci);
    }
    cst[u] = cr;
    cst[256 + u] = cz;
    cst[512 + u] = ci;
    cst[768 + u] = b_hh[512 + u];
  }
}

// ---------------- MFMA GEMM v9: zero-LDS, zero-barrier, direct-L2 B reads ----------------
// Block 128 rows x 64 cols, 4 waves stacked (wave tile 32x64).
// A-frags: plain 16B register loads (v8-verified pattern). B-frags: plain bf16x8
// loads straight from L2 (W matrices are 128-512 KB, L2-resident; all 4 waves read
// identical B rows -> L1 reuse). No global_load_lds, no __syncthreads, no LDS.
// XCD-chunk swizzle keeps a strip's CT col-tiles on one XCD (A L2-reuse).
template <int CT, bool GRUE>
__global__ __launch_bounds__(256, 4) void gemm_v9(const short* __restrict__ A,
                                                  const short* __restrict__ B,
                                                  const float* __restrict__ bias,
                                                  const float* __restrict__ cst,
                                                  short* __restrict__ outH,
                                                  float* __restrict__ outF) {
  const int nwg = gridDim.x;
  const int xcd = blockIdx.x & 7, jj = blockIdx.x >> 3;
  const int q = nwg >> 3, r = nwg & 7;
  const int lidx = (xcd < r ? xcd * (q + 1) : r * (q + 1) + (xcd - r) * q) + jj;
  const int strip = lidx / CT;
  const int ct = lidx % CT;
  const int row0 = strip * 128;
  const int col0 = ct * 64;

  const int tid = threadIdx.x;
  const int l = tid & 63, wm = tid >> 6;   // 4 waves = 4 row-subtiles of 32
  const int fr = l & 15, fg = l >> 4;

  int arow0 = row0 + wm * 32 + fr;       arow0 = arow0 < NN ? arow0 : NN - 1;
  int arow1 = row0 + wm * 32 + 16 + fr;  arow1 = arow1 < NN ? arow1 : NN - 1;
  const short* Ap0 = A + (size_t)arow0 * HID + fg * 8;
  const short* Ap1 = A + (size_t)arow1 * HID + fg * 8;
  const short* Bp0 = B + (size_t)(col0 +  0 + fr) * HID + fg * 8;
  const short* Bp1 = B + (size_t)(col0 + 16 + fr) * HID + fg * 8;
  const short* Bp2 = B + (size_t)(col0 + 32 + fr) * HID + fg * 8;
  const short* Bp3 = B + (size_t)(col0 + 48 + fr) * HID + fg * 8;

  f32x4 acc[2][4];
#pragma unroll
  for (int i = 0; i < 2; ++i)
#pragma unroll
    for (int j = 0; j < 4; ++j) acc[i][j] = (f32x4)(0.0f);

#pragma unroll
  for (int t = 0; t < 8; ++t) {
    const int ko = t * 32;
    bf16x8 a0 = *(const bf16x8*)(Ap0 + ko);
    bf16x8 a1 = *(const bf16x8*)(Ap1 + ko);
    bf16x8 b0 = *(const bf16x8*)(Bp0 + ko);
    bf16x8 b1 = *(const bf16x8*)(Bp1 + ko);
    bf16x8 b2 = *(const bf16x8*)(Bp2 + ko);
    bf16x8 b3 = *(const bf16x8*)(Bp3 + ko);
    acc[0][0] = __builtin_amdgcn_mfma_f32_16x16x32_bf16(a0, b0, acc[0][0], 0, 0, 0);
    acc[0][1] = __builtin_amdgcn_mfma_f32_16x16x32_bf16(a0, b1, acc[0][1], 0, 0, 0);
    acc[0][2] = __builtin_amdgcn_mfma_f32_16x16x32_bf16(a0, b2, acc[0][2], 0, 0, 0);
    acc[0][3] = __builtin_amdgcn_mfma_f32_16x16x32_bf16(a0, b3, acc[0][3], 0, 0, 0);
    acc[1][0] = __builtin_amdgcn_mfma_f32_16x16x32_bf16(a1, b0, acc[1][0], 0, 0, 0);
    acc[1][1] = __builtin_amdgcn_mfma_f32_16x16x32_bf16(a1, b1, acc[1][1], 0, 0, 0);
    acc[1][2] = __builtin_amdgcn_mfma_f32_16x16x32_bf16(a1, b2, acc[1][2], 0, 0, 0);
    acc[1][3] = __builtin_amdgcn_mfma_f32_16x16x32_bf16(a1, b3, acc[1][3], 0, 0, 0);
  }

  if constexpr (!GRUE) {
#pragma unroll
    for (int mf = 0; mf < 2; ++mf) {
      int rbase = row0 + wm * 32 + mf * 16 + fg * 4;
#pragma unroll
      for (int nf = 0; nf < 4; ++nf) {
        int c = col0 + nf * 16 + fr;
        float bs = bias[c];
#pragma unroll
        for (int j = 0; j < 4; ++j) {
          int row = rbase + j;
          if (row < NN) {
            float v = fmaxf(acc[mf][nf][j] + bs, 0.0f);
            outH[(size_t)row * HID + c] = (short)f2bf(v);
          }
        }
      }
    }
  } else {
    // wave col window 64 = all 4 gates (nf) of 16 units (fr); u = ct*16 + fr
    const int u = ct * 16 + fr;
    const float cr = cst[u], cz = cst[256 + u], ci = cst[512 + u], chn = cst[768 + u];
#pragma unroll
    for (int mf = 0; mf < 2; ++mf) {
      int rbase = row0 + wm * 32 + mf * 16 + fg * 4;
#pragma unroll
      for (int j = 0; j < 4; ++j) {
        int row = rbase + j;
        if (row < NN) {
          float dr = acc[mf][0][j] + cr;
          float dz = acc[mf][1][j] + cz;
          float dn = acc[mf][2][j] + ci;
          float dh = acc[mf][3][j] + chn;
          float rg = fast_sig(dr);
          float zg = fast_sig(dz);
          float ng = fast_tanh(dn + rg * dh);
          size_t off = (size_t)row * HID + u;
          float hv = bf2f((unsigned short)A[off]);
          outF[off] = (1.0f - zg) * ng + zg * hv;
        }
      }
    }
  }
}

extern "C" void kernel_launch(void* const* d_in, const int* in_sizes, int n_in,
                              void* d_out, int out_size, void* d_ws, size_t ws_size,
                              hipStream_t stream) {
  const float* hidden = (const float*)d_in[0];
  const float* t      = (const float*)d_in[1];
  const int*   src    = (const int*)d_in[2];
  const int*   dst    = (const int*)d_in[3];
  const float* W1     = (const float*)d_in[4];
  const float* b1     = (const float*)d_in[5];
  const float* W2     = (const float*)d_in[6];
  const float* b2     = (const float*)d_in[7];
  const float* time_w = (const float*)d_in[8];
  const float* time_b = (const float*)d_in[9];
  const float* W_ih   = (const float*)d_in[10];
  const float* W_hh   = (const float*)d_in[11];
  const float* b_ih   = (const float*)d_in[12];
  const float* b_hh   = (const float*)d_in[13];
  float* out = (float*)d_out;

  char* p = (char*)d_ws;
  float* onorm = (float*)p;      p += 50048 * 4;
  float* inorm = (float*)p;      p += 50048 * 4;
  float* cst   = (float*)p;      p += 1024 * 4;
  int* rowstart = (int*)p;       p += 50052 * 4;
  int* icnt     = (int*)p;       p += 50048 * 4;
  int* ecol     = (int*)p;       p += 800000 * 4;
  float* ewt    = (float*)p;     p += 800000 * 4;
  const size_t NFE = (size_t)NN * HID;
  short* Xb   = (short*)p;       p += NFE * 2;
  short* aggB = (short*)p;       p += NFE * 2;
  short* h1B  = (short*)p;       p += NFE * 2;
  short* h2B  = (short*)p;       p += NFE * 2;
  short* W1B  = (short*)p;       p += 65536 * 2;
  short* W2B  = (short*)p;       p += 65536 * 2;
  short* WgB  = (short*)p;       p += 262144 * 2;
  // partial-histogram workspace aliases h2B (8*NSL*CHB ints = 8.4 MB < 25.6 MB);
  // fill_csr2 consumes P before gemm2 first writes h2B (stream-ordered).
  int* P = (int*)h2B;

  // independent prep first
  cvt_hidden<<<(NN * HID / 4 + 255) / 256, 256, 0, stream>>>(hidden, Xb);
  wprep<<<513, 256, 0, stream>>>(W1, W2, W_ih, W_hh, t, time_w, time_b, b_ih, b_hh,
                                 W1B, W2B, WgB, cst);

  // graph prep: privatized histograms -> norms/prefix -> row scan -> LDS-cursor fill
  hist_part<<<8 * NSL, 1024, 0, stream>>>(src, dst, P);
  hist_reduce<<<(4 * CHB + 255) / 256, 256, 0, stream>>>(P, onorm, inorm, icnt);
  scan_rows<<<1, 1024, 0, stream>>>(icnt, rowstart);
  fill_csr2<<<4 * NSL, 1024, 0, stream>>>(src, dst, onorm, rowstart, P, ecol, ewt);

  const int gather_blocks = (NN + 3) / 4;
  const int strips = (NN + 127) / 128;   // 391

  // layer 1: gather + zero-LDS GEMM (CT=4 col-tiles of 64 over 256 cols)
  gather_agg<<<gather_blocks, 256, 0, stream>>>(Xb, rowstart, ecol, ewt, inorm, aggB);
  gemm_v9<4, false><<<strips * 4, 256, 0, stream>>>(aggB, W1B, b1, nullptr, h1B, nullptr);

  // layer 2
  gather_agg<<<gather_blocks, 256, 0, stream>>>(h1B, rowstart, ecol, ewt, inorm, aggB);
  gemm_v9<4, false><<<strips * 4, 256, 0, stream>>>(aggB, W2B, b2, nullptr, h2B, nullptr);

  // GRU: CT=16 (64-col gate-panels over 1024 Wg cols), fused gate epilogue -> out
  gemm_v9<16, true><<<strips * 16, 256, 0, stream>>>(h2B, WgB, nullptr, cst, nullptr, out);
}

// Round 16
// 362.350 us; speedup vs baseline: 1.4049x; 1.3642x over previous
//
#include <hip/hip_runtime.h>
#include <cstdint>
#include <cstddef>

#define NN 50000
#define NE 800000
#define HID 256
#define TDIM 128

#define CHB 16384          // bins per histogram chunk (64 KB LDS)
#define NSL 16             // edge slices
#define SLE (NE / NSL)     // 50000 edges per slice

typedef short bf16x8 __attribute__((ext_vector_type(8)));
typedef float f32x4 __attribute__((ext_vector_type(4)));

#define GLOAD_LDS16(g, l)                                                        \
  __builtin_amdgcn_global_load_lds(                                              \
      (const __attribute__((address_space(1))) unsigned int*)(g),                \
      (__attribute__((address_space(3))) unsigned int*)(l), 16, 0, 0)

__device__ inline unsigned short f2bf(float f) {
  uint32_t u = __builtin_bit_cast(uint32_t, f);
  uint32_t r = u + 0x7FFFu + ((u >> 16) & 1u);
  return (unsigned short)(r >> 16);
}
__device__ inline float bf2f(unsigned short s) {
  uint32_t u = ((uint32_t)s) << 16;
  return __builtin_bit_cast(float, u);
}
__device__ inline float fast_sig(float x) {
  return __builtin_amdgcn_rcpf(1.0f + __expf(-x));
}
__device__ inline float fast_tanh(float x) {
  float xc = fminf(fmaxf(x, -10.0f), 10.0f);
  float e = __expf(2.0f * xc);
  return 1.0f - 2.0f * __builtin_amdgcn_rcpf(e + 1.0f);
}

// ---------------- hidden -> bf16 plane ----------------
__global__ __launch_bounds__(256) void cvt_hidden(const float* __restrict__ x,
                                                  short* __restrict__ xb) {
  int i = blockIdx.x * 256 + threadIdx.x;
  if (i < NN * HID / 4) {
    float4 v = ((const float4*)x)[i];
    unsigned int lo = (unsigned int)f2bf(v.x) | ((unsigned int)f2bf(v.y) << 16);
    unsigned int hi = (unsigned int)f2bf(v.z) | ((unsigned int)f2bf(v.w) << 16);
    ((uint2*)xb)[i] = make_uint2(lo, hi);
  }
}

// ---------------- histogram phase A ----------------
__global__ __launch_bounds__(1024) void hist_part(const int* __restrict__ src,
                                                  const int* __restrict__ dst,
                                                  int* __restrict__ P) {
  __shared__ int h[CHB];
  const int b = blockIdx.x;          // 8 * NSL blocks
  const int c = b & 7, s = b >> 3;
  for (int j = threadIdx.x; j < CHB; j += 1024) h[j] = 0;
  __syncthreads();
  const int* arr = (c < 4) ? src : dst;
  const int base = (c & 3) * CHB;
  const int e0 = s * SLE;
  for (int i = threadIdx.x; i < SLE; i += 1024) {
    int v = arr[e0 + i] - base;
    if ((unsigned)v < CHB) atomicAdd(&h[v], 1);
  }
  __syncthreads();
  int* Pc = P + (size_t)(c * NSL + s) * CHB;
  for (int j = threadIdx.x; j < CHB; j += 1024) Pc[j] = h[j];
}

// ---------------- phase B: reduce -> norms; in-place slice scan ----------------
__global__ __launch_bounds__(256) void hist_reduce(int* __restrict__ P,
                                                   float* __restrict__ onorm,
                                                   float* __restrict__ inorm,
                                                   int* __restrict__ icnt) {
  int n = blockIdx.x * 256 + threadIdx.x;
  if (n >= 4 * CHB) return;
  const int c = n >> 14, j = n & (CHB - 1);
  int* Po = P + (size_t)(c * NSL) * CHB + j;
  int od = 0;
#pragma unroll
  for (int s = 0; s < NSL; ++s) od += Po[(size_t)s * CHB];
  int* Pi = P + (size_t)((4 + c) * NSL) * CHB + j;
  int run = 0;
#pragma unroll
  for (int s = 0; s < NSL; ++s) { int t = Pi[(size_t)s * CHB]; Pi[(size_t)s * CHB] = run; run += t; }
  if (n < NN) {
    onorm[n] = 1.0f / sqrtf(fmaxf((float)od, 1.0f));
    inorm[n] = 1.0f / sqrtf(fmaxf((float)run, 1.0f));
    icnt[n] = run;
  }
}

// ---------------- CSR row scan ----------------
__global__ __launch_bounds__(1024) void scan_rows(const int* __restrict__ icnt,
                                                  int* __restrict__ rowstart) {
  __shared__ int wsum[16];
  __shared__ int carry_s;
  const int tid = threadIdx.x, lane = tid & 63, w = tid >> 6;
  if (tid == 0) { carry_s = 0; rowstart[0] = 0; }
  __syncthreads();
  for (int base = 0; base < NN; base += 8192) {
    int i0 = base + tid * 8;
    int c[8];
    int v = 0;
#pragma unroll
    for (int j = 0; j < 8; ++j) {
      int i = i0 + j;
      c[j] = (i < NN) ? icnt[i] : 0;
      v += c[j];
    }
    int inc = v;
#pragma unroll
    for (int off = 1; off < 64; off <<= 1) {
      int t = __shfl_up(inc, off, 64);
      if (lane >= off) inc += t;
    }
    if (lane == 63) wsum[w] = inc;
    __syncthreads();
    int woff = 0;
    for (int k = 0; k < w; ++k) woff += wsum[k];
    int carry = carry_s;
    int run = carry + woff + inc - v;
#pragma unroll
    for (int j = 0; j < 8; ++j) {
      int i = i0 + j;
      if (i < NN) rowstart[i + 1] = run + c[j];
      run += c[j];
    }
    __syncthreads();
    if (tid == 1023) carry_s = carry + woff + inc;
    __syncthreads();
  }
}

// ---------------- CSR fill via LDS cursors ----------------
__global__ __launch_bounds__(1024) void fill_csr2(const int* __restrict__ src,
                                                  const int* __restrict__ dst,
                                                  const float* __restrict__ onorm,
                                                  const int* __restrict__ rowstart,
                                                  const int* __restrict__ P,
                                                  int* __restrict__ col,
                                                  float* __restrict__ ewt) {
  __shared__ int cur[CHB];
  const int b = blockIdx.x;          // 4 * NSL blocks
  const int c = b & 3, s = b >> 2;
  const int base = c * CHB;
  const int* Pi = P + (size_t)((4 + c) * NSL + s) * CHB;
  for (int j = threadIdx.x; j < CHB; j += 1024) {
    int n = base + j;
    cur[j] = (n < NN ? rowstart[n] : 0) + Pi[j];
  }
  __syncthreads();
  const int e0 = s * SLE;
  for (int i = threadIdx.x; i < SLE; i += 1024) {
    int d = dst[e0 + i] - base;
    if ((unsigned)d < CHB) {
      int sv = src[e0 + i];
      int pos = atomicAdd(&cur[d], 1);
      col[pos] = sv;
      ewt[pos] = onorm[sv];
    }
  }
}

// ---------------- gather aggregation (bf16 in -> bf16 out), 8-edge unroll ----------------
__global__ __launch_bounds__(256) void gather_agg(const short* __restrict__ xB,
                                                  const int* __restrict__ rowstart,
                                                  const int* __restrict__ col,
                                                  const float* __restrict__ ewt,
                                                  const float* __restrict__ inorm,
                                                  short* __restrict__ aggB) {
  const int wid = blockIdx.x * 4 + (threadIdx.x >> 6);
  const int lane = threadIdx.x & 63;
  if (wid >= NN) return;
  const int e1 = rowstart[wid + 1];
  int e = rowstart[wid];
  const int fo = lane * 4;
  float a[4] = {0.f, 0.f, 0.f, 0.f};
  for (; e + 8 <= e1; e += 8) {
    int ss[8]; float ww[8]; uint2 uu[8];
#pragma unroll
    for (int q = 0; q < 8; ++q) { ss[q] = col[e + q]; ww[q] = ewt[e + q]; }
#pragma unroll
    for (int q = 0; q < 8; ++q) uu[q] = *(const uint2*)(xB + (size_t)ss[q] * HID + fo);
#pragma unroll
    for (int q = 0; q < 8; ++q) {
      a[0] = fmaf(bf2f((unsigned short)(uu[q].x & 0xFFFF)), ww[q], a[0]);
      a[1] = fmaf(bf2f((unsigned short)(uu[q].x >> 16)),    ww[q], a[1]);
      a[2] = fmaf(bf2f((unsigned short)(uu[q].y & 0xFFFF)), ww[q], a[2]);
      a[3] = fmaf(bf2f((unsigned short)(uu[q].y >> 16)),    ww[q], a[3]);
    }
  }
  for (; e + 2 <= e1; e += 2) {
    int s0 = col[e], s1 = col[e + 1];
    float w0 = ewt[e], w1 = ewt[e + 1];
    uint2 u0 = *(const uint2*)(xB + (size_t)s0 * HID + fo);
    uint2 u1 = *(const uint2*)(xB + (size_t)s1 * HID + fo);
    a[0] = fmaf(bf2f((unsigned short)(u0.x & 0xFFFF)), w0, a[0]);
    a[1] = fmaf(bf2f((unsigned short)(u0.x >> 16)),    w0, a[1]);
    a[2] = fmaf(bf2f((unsigned short)(u0.y & 0xFFFF)), w0, a[2]);
    a[3] = fmaf(bf2f((unsigned short)(u0.y >> 16)),    w0, a[3]);
    a[0] = fmaf(bf2f((unsigned short)(u1.x & 0xFFFF)), w1, a[0]);
    a[1] = fmaf(bf2f((unsigned short)(u1.x >> 16)),    w1, a[1]);
    a[2] = fmaf(bf2f((unsigned short)(u1.y & 0xFFFF)), w1, a[2]);
    a[3] = fmaf(bf2f((unsigned short)(u1.y >> 16)),    w1, a[3]);
  }
  if (e < e1) {
    int s0 = col[e];
    float w0 = ewt[e];
    uint2 u0 = *(const uint2*)(xB + (size_t)s0 * HID + fo);
    a[0] = fmaf(bf2f((unsigned short)(u0.x & 0xFFFF)), w0, a[0]);
    a[1] = fmaf(bf2f((unsigned short)(u0.x >> 16)),    w0, a[1]);
    a[2] = fmaf(bf2f((unsigned short)(u0.y & 0xFFFF)), w0, a[2]);
    a[3] = fmaf(bf2f((unsigned short)(u0.y >> 16)),    w0, a[3]);
  }
  const float wi = inorm[wid];
  unsigned int lo = (unsigned int)f2bf(a[0] * wi) | ((unsigned int)f2bf(a[1] * wi) << 16);
  unsigned int hi = (unsigned int)f2bf(a[2] * wi) | ((unsigned int)f2bf(a[3] * wi) << 16);
  *(uint2*)(aggB + (size_t)wid * HID + fo) = make_uint2(lo, hi);
}

// ---------------- fused weight prep ----------------
__global__ __launch_bounds__(256) void wprep(const float* __restrict__ W1,
                                             const float* __restrict__ W2,
                                             const float* __restrict__ W_ih,
                                             const float* __restrict__ W_hh,
                                             const float* __restrict__ t,
                                             const float* __restrict__ tw,
                                             const float* __restrict__ tb,
                                             const float* __restrict__ b_ih,
                                             const float* __restrict__ b_hh,
                                             short* __restrict__ W1B,
                                             short* __restrict__ W2B,
                                             short* __restrict__ WgB,
                                             float* __restrict__ cst) {
  const int b = blockIdx.x;
  const int k = threadIdx.x;
  if (b < 256) {
    W1B[b * 256 + k] = (short)f2bf(W1[k * 256 + b]);
    W2B[b * 256 + k] = (short)f2bf(W2[k * 256 + b]);
  } else if (b < 512) {
    int u = b - 256;
    int base = (u >> 4) * 64 + (u & 15);
    float v0 = W_ih[(size_t)u * 384 + k] + W_hh[(size_t)u * 256 + k];
    float v1 = W_ih[(size_t)(256 + u) * 384 + k] + W_hh[(size_t)(256 + u) * 256 + k];
    float v2 = W_ih[(size_t)(512 + u) * 384 + k];
    float v3 = W_hh[(size_t)(512 + u) * 256 + k];
    WgB[(size_t)(base + 0)  * 256 + k] = (short)f2bf(v0);
    WgB[(size_t)(base + 16) * 256 + k] = (short)f2bf(v1);
    WgB[(size_t)(base + 32) * 256 + k] = (short)f2bf(v2);
    WgB[(size_t)(base + 48) * 256 + k] = (short)f2bf(v3);
  } else {
    __shared__ float te[TDIM];
    int u = k;
    if (u < TDIM) te[u] = cosf(t[0] * tw[u] + tb[u]);
    __syncthreads();
    float cr = b_ih[u] + b_hh[u];
    float cz = b_ih[256 + u] + b_hh[256 + u];
    float ci = b_ih[512 + u];
    for (int kk = 0; kk < TDIM; ++kk) {
      float tk = te[kk];
      cr = fmaf(tk, W_ih[(size_t)u * 384 + 256 + kk], cr);
      cz = fmaf(tk, W_ih[(size_t)(256 + u) * 384 + 256 + kk], cz);
      ci = fmaf(tk, W_ih[(size_t)(512 + u) * 384 + 256 + kk], ci);
    }
    cst[u] = cr;
    cst[256 + u] = cz;
    cst[512 + u] = ci;
    cst[768 + u] = b_hh[512 + u];
  }
}

// ---------------- panel GEMM: A block-resident in registers, weight panels loop ----------------
// 64-row blocks (782), 4 waves x 16 rows. Each lane loads its 8 A-frags ONCE (64 VGPR,
// live across kernel) -> A logical traffic = 25.6 MB total per GEMM (was CTx25.6).
// NP weight panels (64 cols x 256 K = 32 KB, v8-verified XOR swizzle) through ONE 32 KB
// LDS buffer: compute(p) -> sync -> stage(p+1) -> sync. Per-panel epilogue.
// GRUE: panel = one gate-block (u = p*16+fr), fused gates -> fp32 out, carry = bf16 A row.
template <int NP, bool GRUE>
__global__ __launch_bounds__(256, 3) void panel_gemm(const short* __restrict__ A,
                                                     const short* __restrict__ WB,
                                                     const float* __restrict__ bias,
                                                     const float* __restrict__ cst,
                                                     short* __restrict__ outH,
                                                     float* __restrict__ outF) {
  __shared__ __align__(16) short Ps[64 * 256];   // 32 KB

  const int row0 = blockIdx.x * 64;
  const int tid = threadIdx.x;
  const int l = tid & 63, w = tid >> 6;
  const int fr = l & 15, fg = l >> 4;

  // stage panel 0 (v8-verified: linear LDS dest, XOR pre-swizzled source)
#pragma unroll
  for (int i = 0; i < 8; ++i) {
    int id = tid + i * 256;
    int row = id >> 5, kc = id & 31;
    GLOAD_LDS16(WB + (size_t)row * HID + ((kc ^ (row & 15)) << 3), Ps + id * 8);
  }

  // A-frags -> registers ONCE (v8-verified pattern; 16 rows per wave)
  int ar = row0 + w * 16 + fr;
  ar = ar < NN ? ar : NN - 1;
  bf16x8 af[8];
#pragma unroll
  for (int t = 0; t < 8; ++t)
    af[t] = *(const bf16x8*)(A + (size_t)ar * HID + t * 32 + fg * 8);

  __syncthreads();   // panel 0 + A-frags landed

#pragma unroll
  for (int p = 0; p < NP; ++p) {
    f32x4 acc[4];
    acc[0] = acc[1] = acc[2] = acc[3] = (f32x4)(0.0f);
#pragma unroll
    for (int t = 0; t < 8; ++t) {
#pragma unroll
      for (int nf = 0; nf < 4; ++nf) {
        int rr = nf * 16 + fr;
        bf16x8 bh = *(const bf16x8*)(Ps + rr * 256 + (((t * 4 + fg) ^ (rr & 15)) << 3));
        acc[nf] = __builtin_amdgcn_mfma_f32_16x16x32_bf16(af[t], bh, acc[nf], 0, 0, 0);
      }
    }

    if constexpr (!GRUE) {
#pragma unroll
      for (int nf = 0; nf < 4; ++nf) {
        int c = p * 64 + nf * 16 + fr;
        float bs = bias[c];
#pragma unroll
        for (int j = 0; j < 4; ++j) {
          int row = row0 + w * 16 + fg * 4 + j;
          if (row < NN) {
            float v = fmaxf(acc[nf][j] + bs, 0.0f);
            outH[(size_t)row * HID + c] = (short)f2bf(v);
          }
        }
      }
    } else {
      const int u = p * 16 + fr;
      const float cr = cst[u], cz = cst[256 + u], ci = cst[512 + u], chn = cst[768 + u];
#pragma unroll
      for (int j = 0; j < 4; ++j) {
        int row = row0 + w * 16 + fg * 4 + j;
        if (row < NN) {
          float dr = acc[0][j] + cr;
          float dz = acc[1][j] + cz;
          float dn = acc[2][j] + ci;
          float dh = acc[3][j] + chn;
          float rg = fast_sig(dr);
          float zg = fast_sig(dz);
          float ng = fast_tanh(dn + rg * dh);
          size_t off = (size_t)row * HID + u;
          float hv = bf2f((unsigned short)A[off]);
          outF[off] = (1.0f - zg) * ng + zg * hv;
        }
      }
    }

    if (p + 1 < NP) {
      __syncthreads();   // all waves done reading Ps
#pragma unroll
      for (int i = 0; i < 8; ++i) {
        int id = tid + i * 256;
        int row = id >> 5, kc = id & 31;
        GLOAD_LDS16(WB + (size_t)((p + 1) * 64 + row) * HID + ((kc ^ (row & 15)) << 3),
                    Ps + id * 8);
      }
      __syncthreads();   // next panel landed (implicit vmcnt drain)
    }
  }
}

extern "C" void kernel_launch(void* const* d_in, const int* in_sizes, int n_in,
                              void* d_out, int out_size, void* d_ws, size_t ws_size,
                              hipStream_t stream) {
  const float* hidden = (const float*)d_in[0];
  const float* t      = (const float*)d_in[1];
  const int*   src    = (const int*)d_in[2];
  const int*   dst    = (const int*)d_in[3];
  const float* W1     = (const float*)d_in[4];
  const float* b1     = (const float*)d_in[5];
  const float* W2     = (const float*)d_in[6];
  const float* b2     = (const float*)d_in[7];
  const float* time_w = (const float*)d_in[8];
  const float* time_b = (const float*)d_in[9];
  const float* W_ih   = (const float*)d_in[10];
  const float* W_hh   = (const float*)d_in[11];
  const float* b_ih   = (const float*)d_in[12];
  const float* b_hh   = (const float*)d_in[13];
  float* out = (float*)d_out;

  char* p = (char*)d_ws;
  float* onorm = (float*)p;      p += 50048 * 4;
  float* inorm = (float*)p;      p += 50048 * 4;
  float* cst   = (float*)p;      p += 1024 * 4;
  int* rowstart = (int*)p;       p += 50052 * 4;
  int* icnt     = (int*)p;       p += 50048 * 4;
  int* ecol     = (int*)p;       p += 800000 * 4;
  float* ewt    = (float*)p;     p += 800000 * 4;
  const size_t NFE = (size_t)NN * HID;
  short* Xb   = (short*)p;       p += NFE * 2;
  short* aggB = (short*)p;       p += NFE * 2;
  short* h1B  = (short*)p;       p += NFE * 2;
  short* h2B  = (short*)p;       p += NFE * 2;
  short* W1B  = (short*)p;       p += 65536 * 2;
  short* W2B  = (short*)p;       p += 65536 * 2;
  short* WgB  = (short*)p;       p += 262144 * 2;
  // partial-histogram workspace aliases h2B (8*NSL*CHB ints = 8.4 MB < 25.6 MB);
  // fill_csr2 consumes P before layer-2 GEMM first writes h2B (stream-ordered).
  int* P = (int*)h2B;

  // independent prep first
  cvt_hidden<<<(NN * HID / 4 + 255) / 256, 256, 0, stream>>>(hidden, Xb);
  wprep<<<513, 256, 0, stream>>>(W1, W2, W_ih, W_hh, t, time_w, time_b, b_ih, b_hh,
                                 W1B, W2B, WgB, cst);

  // graph prep: privatized histograms -> norms/prefix -> row scan -> LDS-cursor fill
  hist_part<<<8 * NSL, 1024, 0, stream>>>(src, dst, P);
  hist_reduce<<<(4 * CHB + 255) / 256, 256, 0, stream>>>(P, onorm, inorm, icnt);
  scan_rows<<<1, 1024, 0, stream>>>(icnt, rowstart);
  fill_csr2<<<4 * NSL, 1024, 0, stream>>>(src, dst, onorm, rowstart, P, ecol, ewt);

  const int gather_blocks = (NN + 3) / 4;
  const int gblocks = (NN + 63) / 64;   // 782

  // layer 1: gather + A-resident panel GEMM (4 panels over 256 cols)
  gather_agg<<<gather_blocks, 256, 0, stream>>>(Xb, rowstart, ecol, ewt, inorm, aggB);
  panel_gemm<4, false><<<gblocks, 256, 0, stream>>>(aggB, W1B, b1, nullptr, h1B, nullptr);

  // layer 2
  gather_agg<<<gather_blocks, 256, 0, stream>>>(h1B, rowstart, ecol, ewt, inorm, aggB);
  panel_gemm<4, false><<<gblocks, 256, 0, stream>>>(aggB, W2B, b2, nullptr, h2B, nullptr);

  // GRU: 16 gate panels over 1024 Wg cols, fused gate epilogue -> out
  panel_gemm<16, true><<<gblocks, 256, 0, stream>>>(h2B, WgB, nullptr, cst, nullptr, out);
}